// Round 1
// baseline (61.792 us; speedup 1.0000x reference)
//
#include <hip/hip_runtime.h>
#include <hip/hip_bf16.h>

#define M_DIM 4096
#define N_DIM 4096
#define K_DIM 1024

typedef short short8 __attribute__((ext_vector_type(8)));
typedef unsigned short ushort8 __attribute__((ext_vector_type(8)));
typedef float f32x4 __attribute__((ext_vector_type(4)));

// fp32 -> bf16, round-to-nearest-even (bias-free; truncation would bias the K-sum)
__device__ __forceinline__ unsigned short f2bf_rne(float f) {
    union { float f; unsigned u; } v;
    v.f = f;
    unsigned u = v.u;
    u += 0x7FFFu + ((u >> 16) & 1u);
    return (unsigned short)(u >> 16);
}

// async global->LDS, 16B per lane. LDS dest is wave-uniform base + lane*16.
__device__ __forceinline__ void gload16(const void* g, void* l) {
    __builtin_amdgcn_global_load_lds(
        (const __attribute__((address_space(1))) void*)g,
        (__attribute__((address_space(3))) void*)l,
        16, 0, 0);
}

// ---- convert A: M x K fp32 -> bf16, same layout. 8 elems/thread. ----
__global__ __launch_bounds__(256) void cvtA_kernel(const float* __restrict__ src,
                                                   unsigned short* __restrict__ dst) {
    size_t i = (size_t)blockIdx.x * 256 + threadIdx.x; // one per 8 elems, grid sized exactly
    const float4* s = (const float4*)src + i * 2;
    float4 v0 = s[0], v1 = s[1];
    ushort8 o;
    o[0] = f2bf_rne(v0.x); o[1] = f2bf_rne(v0.y);
    o[2] = f2bf_rne(v0.z); o[3] = f2bf_rne(v0.w);
    o[4] = f2bf_rne(v1.x); o[5] = f2bf_rne(v1.y);
    o[6] = f2bf_rne(v1.z); o[7] = f2bf_rne(v1.w);
    *(ushort8*)(dst + i * 8) = o;
}

// ---- convert+transpose B: K x N fp32 -> Bt: N x K bf16. 32x32 LDS tile. ----
__global__ __launch_bounds__(256) void cvtBT_kernel(const float* __restrict__ B,
                                                    unsigned short* __restrict__ Bt) {
    __shared__ unsigned short tile[32][33]; // +1 pad
    int x = threadIdx.x, y = threadIdx.y;   // block (32,8)
    int n0 = blockIdx.x * 32, k0 = blockIdx.y * 32;
#pragma unroll
    for (int j = 0; j < 4; ++j) {
        int k = k0 + y + j * 8;
        tile[y + j * 8][x] = f2bf_rne(B[(size_t)k * N_DIM + n0 + x]);
    }
    __syncthreads();
#pragma unroll
    for (int j = 0; j < 4; ++j) {
        int n = n0 + y + j * 8;
        Bt[(size_t)n * K_DIM + k0 + x] = tile[x][y + j * 8];
    }
}

// ---- main GEMM: C[M][N] fp32 = A[M][K] bf16 * Bt[N][K] bf16 ----
// 128x128 tile, BK=64, 4 waves 2x2, each wave 64x64 = 4x4 16x16x32 MFMA frags.
// LDS [row][64 bf16] with 16B-slot XOR swizzle (slot ^= row&7); staged via
// global_load_lds with inverse-swizzled per-lane SOURCE address (linear dest).
__global__ __launch_bounds__(256) void gemm_kernel(const unsigned short* __restrict__ A,
                                                   const unsigned short* __restrict__ Bt,
                                                   float* __restrict__ C) {
    __shared__ unsigned short sA[128 * 64];
    __shared__ unsigned short sB[128 * 64];

    // XCD-aware bijective swizzle: 1024 blocks, 8 XCDs -> 128 tiles/XCD,
    // each XCD covers 4 tile-rows x 32 tile-cols (A+B panels of a ~32-tile
    // concurrent set ~3MB < 4MiB per-XCD L2).
    int bid = blockIdx.x;
    int xcd = bid & 7;
    int i = bid >> 3;               // 0..127
    int tm = xcd * 4 + (i & 3);     // 0..31
    int tn = i >> 2;                // 0..31
    int bM = tm * 128, bN = tn * 128;

    int tid = threadIdx.x;
    int wid = tid >> 6, lane = tid & 63;
    int wm = wid >> 1, wn = wid & 1;

    // staging: per issue g, 64 lanes x 16B = 8 rows of 128B (linear LDS)
    int srow = lane >> 3;                 // row within issue (0..7)
    int cslot = (lane & 7) ^ srow;        // inverse-swizzled source 16B-slot

    f32x4 acc[4][4];
#pragma unroll
    for (int m = 0; m < 4; ++m)
#pragma unroll
        for (int n = 0; n < 4; ++n)
            acc[m][n] = (f32x4){0.f, 0.f, 0.f, 0.f};

    int rowA = wm * 64 + (lane & 15);
    int rowB = wn * 64 + (lane & 15);
    int rslot = lane >> 4;                // k-slot within k-step

    for (int kt = 0; kt < K_DIM / 64; ++kt) {
        int k0 = kt * 64;
        __syncthreads();  // all waves done reading previous tile
#pragma unroll
        for (int ii = 0; ii < 4; ++ii) {
            int g = wid * 4 + ii;  // wave-uniform issue id, 16 issues cover 16KB
            const unsigned short* ga =
                A + (size_t)(bM + g * 8 + srow) * K_DIM + k0 + cslot * 8;
            gload16(ga, (char*)sA + g * 1024);
            const unsigned short* gb =
                Bt + (size_t)(bN + g * 8 + srow) * K_DIM + k0 + cslot * 8;
            gload16(gb, (char*)sB + g * 1024);
        }
        __syncthreads();  // drains vmcnt -> LDS tiles visible

#pragma unroll
        for (int kk = 0; kk < 2; ++kk) {
            short8 av[4], bv[4];
#pragma unroll
            for (int m = 0; m < 4; ++m) {
                int rA = rowA + m * 16;
                int slA = (kk * 4 + rslot) ^ (rA & 7);
                av[m] = *(const short8*)(sA + rA * 64 + slA * 8);
                int rB = rowB + m * 16;
                int slB = (kk * 4 + rslot) ^ (rB & 7);
                bv[m] = *(const short8*)(sB + rB * 64 + slB * 8);
            }
#pragma unroll
            for (int m = 0; m < 4; ++m)
#pragma unroll
                for (int n = 0; n < 4; ++n)
                    acc[m][n] = __builtin_amdgcn_mfma_f32_16x16x32_bf16(
                        av[m], bv[n], acc[m][n], 0, 0, 0);
        }
    }

    // epilogue: C/D layout col = lane&15, row = (lane>>4)*4 + r  [m89/m91]
    size_t crow = (size_t)bM + wm * 64 + ((lane >> 4) << 2);
    int ccol = bN + wn * 64 + (lane & 15);
#pragma unroll
    for (int m = 0; m < 4; ++m)
#pragma unroll
        for (int n = 0; n < 4; ++n)
#pragma unroll
            for (int r = 0; r < 4; ++r)
                C[(crow + m * 16 + r) * N_DIM + ccol + n * 16] = acc[m][n][r];
}

// ---- fallback: plain fp32 tiled GEMM (only if ws too small; exact) ----
__global__ __launch_bounds__(256) void sgemm_fb(const float* __restrict__ A,
                                                const float* __restrict__ B,
                                                float* __restrict__ C) {
    __shared__ float sA[64][17];
    __shared__ float sB[16][65];
    int tx = threadIdx.x, ty = threadIdx.y; // 16x16
    int bM = blockIdx.y * 64, bN = blockIdx.x * 64;
    int t = ty * 16 + tx;
    float acc[4][4] = {};
    for (int k0 = 0; k0 < K_DIM; k0 += 16) {
        __syncthreads();
#pragma unroll
        for (int e = 0; e < 4; ++e) {
            int idx = t * 4 + e;
            int r = idx >> 4, c = idx & 15;
            sA[r][c] = A[(size_t)(bM + r) * K_DIM + k0 + c];
            int r2 = idx >> 6, c2 = idx & 63;
            sB[r2][c2] = B[(size_t)(k0 + r2) * N_DIM + bN + c2];
        }
        __syncthreads();
#pragma unroll
        for (int k = 0; k < 16; ++k) {
            float ar[4], br[4];
#pragma unroll
            for (int q = 0; q < 4; ++q) { ar[q] = sA[ty * 4 + q][k]; br[q] = sB[k][tx * 4 + q]; }
#pragma unroll
            for (int q = 0; q < 4; ++q)
#pragma unroll
                for (int w = 0; w < 4; ++w)
                    acc[q][w] += ar[q] * br[w];
        }
    }
#pragma unroll
    for (int q = 0; q < 4; ++q)
#pragma unroll
        for (int w = 0; w < 4; ++w)
            C[(size_t)(bM + ty * 4 + q) * N_DIM + bN + tx * 4 + w] = acc[q][w];
}

extern "C" void kernel_launch(void* const* d_in, const int* in_sizes, int n_in,
                              void* d_out, int out_size, void* d_ws, size_t ws_size,
                              hipStream_t stream) {
    const float* A = (const float*)d_in[0];
    const float* B = (const float*)d_in[1];
    float* C = (float*)d_out;

    size_t needA = (size_t)M_DIM * K_DIM * sizeof(unsigned short);
    size_t needB = (size_t)K_DIM * N_DIM * sizeof(unsigned short);

    if (ws_size >= needA + needB) {
        unsigned short* Aw = (unsigned short*)d_ws;
        unsigned short* Bw = Aw + (size_t)M_DIM * K_DIM;
        // A: 4194304 elems / 8 per thread / 256 = 2048 blocks (exact)
        cvtA_kernel<<<2048, 256, 0, stream>>>(A, Aw);
        cvtBT_kernel<<<dim3(N_DIM / 32, K_DIM / 32), dim3(32, 8), 0, stream>>>(B, Bw);
        gemm_kernel<<<(M_DIM / 128) * (N_DIM / 128), 256, 0, stream>>>(Aw, Bw, C);
    } else {
        sgemm_fb<<<dim3(N_DIM / 64, M_DIM / 64), dim3(16, 16), 0, stream>>>(A, B, C);
    }
}

// Round 2
// 50.701 us; speedup vs baseline: 1.2188x; 1.2188x over previous
//
#include <hip/hip_runtime.h>
#include <hip/hip_bf16.h>

#define M_DIM 4096
#define N_DIM 4096
#define K_DIM 1024
#define NT (K_DIM / 64)   // 16 K-tiles of BK=64

typedef short short8 __attribute__((ext_vector_type(8)));
typedef unsigned short ushort8 __attribute__((ext_vector_type(8)));
typedef float f32x4 __attribute__((ext_vector_type(4)));

// fp32 -> bf16 round-to-nearest-even (bias-free over the K-sum)
__device__ __forceinline__ unsigned short f2bf_rne(float f) {
    union { float f; unsigned u; } v;
    v.f = f;
    unsigned u = v.u;
    u += 0x7FFFu + ((u >> 16) & 1u);
    return (unsigned short)(u >> 16);
}

// async global->LDS, 16B/lane. LDS dest = wave-uniform base + lane*16.
__device__ __forceinline__ void gload16(const void* g, void* l) {
    __builtin_amdgcn_global_load_lds(
        (const __attribute__((address_space(1))) void*)g,
        (__attribute__((address_space(3))) void*)l,
        16, 0, 0);
}

// ---- merged conversion: A fp32->bf16 (same layout) + B fp32 -> Bt bf16 (N x K) ----
__global__ __launch_bounds__(256) void cvt_kernel(const float* __restrict__ A,
                                                  const float* __restrict__ B,
                                                  unsigned short* __restrict__ Aw,
                                                  unsigned short* __restrict__ Bw) {
    __shared__ unsigned short tile[32][33];
    if (blockIdx.x < 2048) {
        // A: 4096x1024 = 4194304 elems, 8 per thread, 2048 blocks exact
        size_t i = (size_t)blockIdx.x * 256 + threadIdx.x;
        const float4* s = (const float4*)A + i * 2;
        float4 v0 = s[0], v1 = s[1];
        ushort8 o;
        o[0] = f2bf_rne(v0.x); o[1] = f2bf_rne(v0.y);
        o[2] = f2bf_rne(v0.z); o[3] = f2bf_rne(v0.w);
        o[4] = f2bf_rne(v1.x); o[5] = f2bf_rne(v1.y);
        o[6] = f2bf_rne(v1.z); o[7] = f2bf_rne(v1.w);
        *(ushort8*)(Aw + i * 8) = o;
    } else {
        // B transpose+convert: 32x32 LDS tile; (N/32=128) x (K/32=32) = 4096 blocks
        int bb = blockIdx.x - 2048;
        int bx = bb & 127, by = bb >> 7;
        int x = threadIdx.x & 31, y = threadIdx.x >> 5;   // 32 x 8
        int n0 = bx * 32, k0 = by * 32;
#pragma unroll
        for (int j = 0; j < 4; ++j)
            tile[y + j * 8][x] = f2bf_rne(B[(size_t)(k0 + y + j * 8) * N_DIM + n0 + x]);
        __syncthreads();
#pragma unroll
        for (int j = 0; j < 4; ++j)
            Bw[(size_t)(n0 + y + j * 8) * K_DIM + k0 + x] = tile[x][y + j * 8];
    }
}

// ---- 256x256x64 8-phase GEMM: C fp32 = A(bf16, MxK) * Bt(bf16, NxK) ----
// 8 waves (2M x 4N), per-wave 128x64 out = acc[8][4] 16x16 frags.
// LDS 128 KiB: [buf][A/B][256 rows][64 bf16], 16B-slot XOR swizzle (slot ^= row&7).
// Staging unit = 64 rows = 8KB = 1 gload/thread; 8 units/K-tile; 2 units/phase;
// prefetch 2 K-tiles ahead; vmcnt(6) once per K-tile (tails drain vmcnt(0)).
__global__ __launch_bounds__(512, 2) void gemm8_kernel(const unsigned short* __restrict__ A,
                                                       const unsigned short* __restrict__ Bt,
                                                       float* __restrict__ C) {
    __shared__ __align__(16) unsigned short lds[2][2][256 * 64];  // [buf][0=A,1=B]

    // XCD-aware bijective swizzle: 256 blocks, 8 XCDs, 32 tiles/XCD (2 rows x 16 cols)
    int bid = blockIdx.x;
    int xcd = bid & 7, ii = bid >> 3;
    int tm = xcd * 2 + (ii & 1);
    int tn = ii >> 1;
    int bM = tm * 256, bN = tn * 256;

    int tid = threadIdx.x;
    int wid = tid >> 6, lane = tid & 63;
    int wm = wid >> 2, wn = wid & 3;

    // staging per-thread constants
    int srow = lane >> 3;
    int cslot = (lane & 7) ^ srow;      // inverse-swizzled global 16B-slot
    int stg_row = wid * 8 + srow;       // row within 64-row unit

    const unsigned short* gA = A + (size_t)(bM + stg_row) * K_DIM + cslot * 8;
    const unsigned short* gB = Bt + (size_t)(bN + stg_row) * K_DIM + cslot * 8;

    // stage one 8KB unit (64 rows x 64 k) of mat (0=A,1=B) for K-tile kt into buf
#define STG(mat, unit, buf, kt)                                                        \
    gload16((mat ? gB : gA) + (size_t)((unit) * 64) * K_DIM + (size_t)(kt) * 64,       \
            (char*)&lds[(buf)][(mat)][0] + (unit) * 8192 + wid * 1024)

    // fragment read addressing
    int rA = wm * 128 + (lane & 15);    // + m*16
    int rB = wn * 64 + (lane & 15);     // + n*16
    int rslot = lane >> 4;              // + k*4, then ^ (lane&7)
    int l7 = lane & 7;

#define LDA(buf, m, k) \
    (*(const short8*)&lds[(buf)][0][(rA + (m) * 16) * 64 + ((((k) * 4 + rslot) ^ l7) * 8)])
#define LDB(buf, n, k) \
    (*(const short8*)&lds[(buf)][1][(rB + (n) * 16) * 64 + ((((k) * 4 + rslot) ^ l7) * 8)])

    f32x4 acc[8][4];
#pragma unroll
    for (int m = 0; m < 8; ++m)
#pragma unroll
        for (int n = 0; n < 4; ++n)
            acc[m][n] = (f32x4){0.f, 0.f, 0.f, 0.f};

    short8 av[2][2], bv[4][2];

    // MFMA cluster for one phase (m = MBASE, MBASE+1)
#define PHASE_MFMA(MBASE)                                                              \
    __builtin_amdgcn_s_barrier();                                                      \
    asm volatile("s_waitcnt lgkmcnt(0)" ::: "memory");                                 \
    __builtin_amdgcn_sched_barrier(0);                                                 \
    __builtin_amdgcn_s_setprio(1);                                                     \
    _Pragma("unroll") for (int m2 = 0; m2 < 2; ++m2)                                   \
        _Pragma("unroll") for (int n = 0; n < 4; ++n)                                  \
            _Pragma("unroll") for (int k = 0; k < 2; ++k)                              \
                acc[(MBASE) + m2][n] = __builtin_amdgcn_mfma_f32_16x16x32_bf16(        \
                    av[m2][k], bv[n][k], acc[(MBASE) + m2][n], 0, 0, 0);               \
    __builtin_amdgcn_s_setprio(0);

#define LOAD_AV(buf, MBASE)                                                            \
    _Pragma("unroll") for (int m2 = 0; m2 < 2; ++m2)                                   \
        _Pragma("unroll") for (int k = 0; k < 2; ++k)                                  \
            av[m2][k] = LDA(buf, (MBASE) + m2, k);

    // ---- prologue: tile0 fully + tile1's first 6 units; drain to tile0 resident ----
#pragma unroll
    for (int u = 0; u < 4; ++u) { STG(1, u, 0, 0); }
#pragma unroll
    for (int u = 0; u < 4; ++u) { STG(0, u, 0, 0); }
#pragma unroll
    for (int u = 0; u < 4; ++u) { STG(1, u, 1, 1); }
    STG(0, 0, 1, 1);
    STG(0, 2, 1, 1);
    asm volatile("s_waitcnt vmcnt(6)" ::: "memory");
    __builtin_amdgcn_s_barrier();

    for (int t = 0; t < NT; ++t) {
        int cur = t & 1, nxt = cur ^ 1;

        // ---- phase 0: all B frags + A m0,1 (12 ds_reads); stage t+1's A-u1,u3 ----
#pragma unroll
        for (int n = 0; n < 4; ++n)
#pragma unroll
            for (int k = 0; k < 2; ++k)
                bv[n][k] = LDB(cur, n, k);
        LOAD_AV(cur, 0)
        if (t + 1 < NT) { STG(0, 1, nxt, t + 1); STG(0, 3, nxt, t + 1); }
        PHASE_MFMA(0)
        __builtin_amdgcn_s_barrier();

        // ---- phase 1: A m2,3; stage t+2's B-u0,u1 (B free after ph0) ----
        LOAD_AV(cur, 2)
        if (t + 2 < NT) { STG(1, 0, cur, t + 2); STG(1, 1, cur, t + 2); }
        PHASE_MFMA(2)
        __builtin_amdgcn_s_barrier();

        // ---- phase 2: A m4,5; stage t+2's B-u2,u3 ----
        LOAD_AV(cur, 4)
        if (t + 2 < NT) { STG(1, 2, cur, t + 2); STG(1, 3, cur, t + 2); }
        PHASE_MFMA(4)
        __builtin_amdgcn_s_barrier();

        // ---- phase 3: A m6,7; stage t+2's A-u0,u2 (free after ph1) ----
        LOAD_AV(cur, 6)
        if (t + 2 < NT) { STG(0, 0, cur, t + 2); STG(0, 2, cur, t + 2); }
        PHASE_MFMA(6)
        // ---- K-tile boundary: counted vmcnt -> next tile resident ----
        if (t < NT - 2) {
            asm volatile("s_waitcnt vmcnt(6)" ::: "memory");
        } else if (t == NT - 2) {
            asm volatile("s_waitcnt vmcnt(0)" ::: "memory");
        }
        __builtin_amdgcn_s_barrier();
    }

    // ---- epilogue: C/D layout col=lane&15, row=(lane>>4)*4+r ----
    size_t crow = (size_t)bM + wm * 128 + ((lane >> 4) << 2);
    int ccol = bN + wn * 64 + (lane & 15);
#pragma unroll
    for (int m = 0; m < 8; ++m)
#pragma unroll
        for (int n = 0; n < 4; ++n)
#pragma unroll
            for (int r = 0; r < 4; ++r)
                C[(crow + m * 16 + r) * N_DIM + ccol + n * 16] = acc[m][n][r];
#undef STG
#undef LDA
#undef LDB
#undef PHASE_MFMA
#undef LOAD_AV
}

// ---- fallback: plain fp32 tiled GEMM (only if ws too small; exact) ----
__global__ __launch_bounds__(256) void sgemm_fb(const float* __restrict__ A,
                                                const float* __restrict__ B,
                                                float* __restrict__ C) {
    __shared__ float sA[64][17];
    __shared__ float sB[16][65];
    int tx = threadIdx.x, ty = threadIdx.y;
    int bM = blockIdx.y * 64, bN = blockIdx.x * 64;
    int t = ty * 16 + tx;
    float acc[4][4] = {};
    for (int k0 = 0; k0 < K_DIM; k0 += 16) {
        __syncthreads();
#pragma unroll
        for (int e = 0; e < 4; ++e) {
            int idx = t * 4 + e;
            int r = idx >> 4, c = idx & 15;
            sA[r][c] = A[(size_t)(bM + r) * K_DIM + k0 + c];
            int r2 = idx >> 6, c2 = idx & 63;
            sB[r2][c2] = B[(size_t)(k0 + r2) * N_DIM + bN + c2];
        }
        __syncthreads();
#pragma unroll
        for (int k = 0; k < 16; ++k) {
            float ar[4], br[4];
#pragma unroll
            for (int q = 0; q < 4; ++q) { ar[q] = sA[ty * 4 + q][k]; br[q] = sB[k][tx * 4 + q]; }
#pragma unroll
            for (int q = 0; q < 4; ++q)
#pragma unroll
                for (int w = 0; w < 4; ++w)
                    acc[q][w] += ar[q] * br[w];
        }
    }
#pragma unroll
    for (int q = 0; q < 4; ++q)
#pragma unroll
        for (int w = 0; w < 4; ++w)
            C[(size_t)(bM + ty * 4 + q) * N_DIM + bN + tx * 4 + w] = acc[q][w];
}

extern "C" void kernel_launch(void* const* d_in, const int* in_sizes, int n_in,
                              void* d_out, int out_size, void* d_ws, size_t ws_size,
                              hipStream_t stream) {
    const float* A = (const float*)d_in[0];
    const float* B = (const float*)d_in[1];
    float* C = (float*)d_out;

    size_t needA = (size_t)M_DIM * K_DIM * sizeof(unsigned short);
    size_t needB = (size_t)K_DIM * N_DIM * sizeof(unsigned short);

    if (ws_size >= needA + needB) {
        unsigned short* Aw = (unsigned short*)d_ws;
        unsigned short* Bw = Aw + (size_t)M_DIM * K_DIM;
        cvt_kernel<<<2048 + 4096, 256, 0, stream>>>(A, B, Aw, Bw);
        gemm8_kernel<<<(M_DIM / 256) * (N_DIM / 256), 512, 0, stream>>>(Aw, Bw, C);
    } else {
        sgemm_fb<<<dim3(N_DIM / 64, M_DIM / 64), dim3(16, 16), 0, stream>>>(A, B, C);
    }
}

// Round 3
// 50.651 us; speedup vs baseline: 1.2200x; 1.0010x over previous
//
#include <hip/hip_runtime.h>
#include <hip/hip_bf16.h>

#define M_DIM 4096
#define N_DIM 4096
#define K_DIM 1024
#define NT (K_DIM / 64)   // 16 K-tiles of BK=64

typedef short short8 __attribute__((ext_vector_type(8)));
typedef unsigned short ushort8 __attribute__((ext_vector_type(8)));
typedef float f32x4 __attribute__((ext_vector_type(4)));

// fp32 -> bf16 round-to-nearest-even (bias-free over the K-sum)
__device__ __forceinline__ unsigned short f2bf_rne(float f) {
    union { float f; unsigned u; } v;
    v.f = f;
    unsigned u = v.u;
    u += 0x7FFFu + ((u >> 16) & 1u);
    return (unsigned short)(u >> 16);
}

// async global->LDS, 16B/lane. LDS dest = wave-uniform base + lane*16.
__device__ __forceinline__ void gload16(const void* g, void* l) {
    __builtin_amdgcn_global_load_lds(
        (const __attribute__((address_space(1))) void*)g,
        (__attribute__((address_space(3))) void*)l,
        16, 0, 0);
}

// ---- merged conversion: A fp32->bf16 (same layout) + B fp32 -> Bt bf16 (N x K) ----
__global__ __launch_bounds__(256) void cvt_kernel(const float* __restrict__ A,
                                                  const float* __restrict__ B,
                                                  unsigned short* __restrict__ Aw,
                                                  unsigned short* __restrict__ Bw) {
    __shared__ unsigned short tile[32][33];
    if (blockIdx.x < 2048) {
        size_t i = (size_t)blockIdx.x * 256 + threadIdx.x;
        const float4* s = (const float4*)A + i * 2;
        float4 v0 = s[0], v1 = s[1];
        ushort8 o;
        o[0] = f2bf_rne(v0.x); o[1] = f2bf_rne(v0.y);
        o[2] = f2bf_rne(v0.z); o[3] = f2bf_rne(v0.w);
        o[4] = f2bf_rne(v1.x); o[5] = f2bf_rne(v1.y);
        o[6] = f2bf_rne(v1.z); o[7] = f2bf_rne(v1.w);
        *(ushort8*)(Aw + i * 8) = o;
    } else {
        int bb = blockIdx.x - 2048;
        int bx = bb & 127, by = bb >> 7;
        int x = threadIdx.x & 31, y = threadIdx.x >> 5;
        int n0 = bx * 32, k0 = by * 32;
#pragma unroll
        for (int j = 0; j < 4; ++j)
            tile[y + j * 8][x] = f2bf_rne(B[(size_t)(k0 + y + j * 8) * N_DIM + n0 + x]);
        __syncthreads();
#pragma unroll
        for (int j = 0; j < 4; ++j)
            Bw[(size_t)(n0 + y + j * 8) * K_DIM + k0 + x] = tile[x][y + j * 8];
    }
}

// ---- 256x256x64 pipelined GEMM: C fp32 = A(bf16 MxK) * Bt(bf16 NxK) ----
// 8 waves (2Mx4N), per-wave 128x64 = acc[8][4]. LDS 128 KiB double-buffered,
// 16B-slot XOR swizzle. v4 schedule: ds_reads issued ONE PHASE AHEAD
// (av ping-pong X/Y, bv double-buffer P/Q per tile), single raw s_barrier
// per phase, boundary vmcnt(4) at ph1 (covers all of tile t+1 by issue
// count), STG: ph0 B(t+2)u01, ph1 A(t+2)u02, ph2 B(t+2)u23, ph3 A(t+2)u13.
__global__ __launch_bounds__(512, 2) void gemm8_kernel(const unsigned short* __restrict__ A,
                                                       const unsigned short* __restrict__ Bt,
                                                       float* __restrict__ C) {
    __shared__ __align__(16) unsigned short lds[2][2][256 * 64];  // [buf][0=A,1=B]

    int bid = blockIdx.x;
    int xcd = bid & 7, ii = bid >> 3;
    int tm = xcd * 2 + (ii & 1);
    int tn = ii >> 1;
    int bM = tm * 256, bN = tn * 256;

    int tid = threadIdx.x;
    int wid = tid >> 6, lane = tid & 63;
    int wm = wid >> 2, wn = wid & 3;

    int srow = lane >> 3;
    int cslot = (lane & 7) ^ srow;
    int stg_row = wid * 8 + srow;

    const unsigned short* gA = A + (size_t)(bM + stg_row) * K_DIM + cslot * 8;
    const unsigned short* gB = Bt + (size_t)(bN + stg_row) * K_DIM + cslot * 8;

#define STG(mat, unit, buf, kt)                                                        \
    gload16((mat ? gB : gA) + (size_t)((unit) * 64) * K_DIM + (size_t)(kt) * 64,       \
            (char*)&lds[(buf)][(mat)][0] + (unit) * 8192 + wid * 1024)

    int rA = wm * 128 + (lane & 15);
    int rB = wn * 64 + (lane & 15);
    int rslot = lane >> 4;
    int l7 = lane & 7;

#define LDA(buf, m, k) \
    (*(const short8*)&lds[(buf)][0][(rA + (m) * 16) * 64 + ((((k) * 4 + rslot) ^ l7) * 8)])
#define LDB(buf, n, k) \
    (*(const short8*)&lds[(buf)][1][(rB + (n) * 16) * 64 + ((((k) * 4 + rslot) ^ l7) * 8)])

    f32x4 acc[8][4];
#pragma unroll
    for (int m = 0; m < 8; ++m)
#pragma unroll
        for (int n = 0; n < 4; ++n)
            acc[m][n] = (f32x4){0.f, 0.f, 0.f, 0.f};

    short8 avX[2][2], avY[2][2];      // per-phase ping-pong A fragments
    short8 bvP[4][2], bvQ[4][2];      // per-tile double-buffered B fragments

#define PH_SYNC()                              \
    __builtin_amdgcn_sched_barrier(0);         \
    __builtin_amdgcn_s_barrier();              \
    __builtin_amdgcn_sched_barrier(0);

    // k-outer: 8 independent MFMAs between the two writes to each acc
#define MFMA8(AV, BV, MB)                                                              \
    __builtin_amdgcn_s_setprio(1);                                                     \
    _Pragma("unroll") for (int k = 0; k < 2; ++k)                                      \
        _Pragma("unroll") for (int m2 = 0; m2 < 2; ++m2)                               \
            _Pragma("unroll") for (int n = 0; n < 4; ++n)                              \
                acc[(MB) + m2][n] = __builtin_amdgcn_mfma_f32_16x16x32_bf16(           \
                    AV[m2][k], BV[n][k], acc[(MB) + m2][n], 0, 0, 0);                  \
    __builtin_amdgcn_s_setprio(0);

#define LDAV(AV, BUF, MB)                                                              \
    _Pragma("unroll") for (int m2 = 0; m2 < 2; ++m2)                                   \
        _Pragma("unroll") for (int k = 0; k < 2; ++k)                                  \
            AV[m2][k] = LDA(BUF, (MB) + m2, k);

#define LDBV_K(BV, BUF, KK)                                                            \
    _Pragma("unroll") for (int n = 0; n < 4; ++n)                                      \
        BV[n][KK] = LDB(BUF, n, KK);

    // one K-tile: CB=this tile's buf, NB=next tile's buf (compile-time 0/1)
#define TILE(t, CB, NB, BVC, BVN)                                                      \
    {                                                                                  \
        /* ph0: read av m2,3 | stage B(t+2) u0,u1 | MFMA m0,1 */                       \
        LDAV(avY, CB, 2)                                                               \
        if ((t) + 2 < NT) { STG(1, 0, CB, (t) + 2); STG(1, 1, CB, (t) + 2); }          \
        PH_SYNC();                                                                     \
        MFMA8(avX, BVC, 0)                                                             \
        /* ph1: read av m4,5 | stage A(t+2) u0,u2 | boundary vmcnt | MFMA m2,3 */      \
        LDAV(avX, CB, 4)                                                               \
        if ((t) + 2 < NT) { STG(0, 0, CB, (t) + 2); STG(0, 2, CB, (t) + 2); }          \
        if ((t) < NT - 2) { asm volatile("s_waitcnt vmcnt(4)" ::: "memory"); }         \
        else              { asm volatile("s_waitcnt vmcnt(0)" ::: "memory"); }         \
        PH_SYNC();                                                                     \
        MFMA8(avY, BVC, 2)                                                             \
        /* ph2: read av m6,7 + bvN k0 (nxt buf) | stage B(t+2) u2,u3 | MFMA m4,5 */    \
        LDAV(avY, CB, 6)                                                               \
        if ((t) + 1 < NT) { LDBV_K(BVN, NB, 0) }                                       \
        if ((t) + 2 < NT) { STG(1, 2, CB, (t) + 2); STG(1, 3, CB, (t) + 2); }          \
        PH_SYNC();                                                                     \
        MFMA8(avX, BVC, 4)                                                             \
        /* ph3: read bvN k1 + avX m0,1 (nxt) | stage A(t+2) u1,u3 | MFMA m6,7 */       \
        if ((t) + 1 < NT) { LDBV_K(BVN, NB, 1) LDAV(avX, NB, 0) }                      \
        if ((t) + 2 < NT) { STG(0, 1, CB, (t) + 2); STG(0, 3, CB, (t) + 2); }          \
        PH_SYNC();                                                                     \
        MFMA8(avY, BVC, 6)                                                             \
    }

    // ---- prologue: stage tile0 + tile1 (tile1 in steady-state issue order) ----
#pragma unroll
    for (int u = 0; u < 4; ++u) { STG(1, u, 0, 0); }
#pragma unroll
    for (int u = 0; u < 4; ++u) { STG(0, u, 0, 0); }
    STG(1, 0, 1, 1); STG(1, 1, 1, 1);   // as-if t=-1 ph0
    STG(0, 0, 1, 1); STG(0, 2, 1, 1);   // ph1
    STG(1, 2, 1, 1); STG(1, 3, 1, 1);   // ph2
    STG(0, 1, 1, 1); STG(0, 3, 1, 1);   // ph3
    asm volatile("s_waitcnt vmcnt(8)" ::: "memory");  // tile0 resident
    __builtin_amdgcn_s_barrier();
    // pre-reads for tile0 ph0 (the as-if t=-1 ph2/ph3 reads)
    LDBV_K(bvP, 0, 0)
    LDBV_K(bvP, 0, 1)
    LDAV(avX, 0, 0)

    for (int t = 0; t < NT; t += 2) {
        TILE(t, 0, 1, bvP, bvQ)
        TILE(t + 1, 1, 0, bvQ, bvP)
    }

    // ---- epilogue: C/D layout col=lane&15, row=(lane>>4)*4+r ----
    size_t crow = (size_t)bM + wm * 128 + ((lane >> 4) << 2);
    int ccol = bN + wn * 64 + (lane & 15);
#pragma unroll
    for (int m = 0; m < 8; ++m)
#pragma unroll
        for (int n = 0; n < 4; ++n)
#pragma unroll
            for (int r = 0; r < 4; ++r)
                C[(crow + m * 16 + r) * N_DIM + ccol + n * 16] = acc[m][n][r];
#undef STG
#undef LDA
#undef LDB
#undef PH_SYNC
#undef MFMA8
#undef LDAV
#undef LDBV_K
#undef TILE
}

// ---- fallback: plain fp32 tiled GEMM (only if ws too small; exact) ----
__global__ __launch_bounds__(256) void sgemm_fb(const float* __restrict__ A,
                                                const float* __restrict__ B,
                                                float* __restrict__ C) {
    __shared__ float sA[64][17];
    __shared__ float sB[16][65];
    int tx = threadIdx.x, ty = threadIdx.y;
    int bM = blockIdx.y * 64, bN = blockIdx.x * 64;
    int t = ty * 16 + tx;
    float acc[4][4] = {};
    for (int k0 = 0; k0 < K_DIM; k0 += 16) {
        __syncthreads();
#pragma unroll
        for (int e = 0; e < 4; ++e) {
            int idx = t * 4 + e;
            int r = idx >> 4, c = idx & 15;
            sA[r][c] = A[(size_t)(bM + r) * K_DIM + k0 + c];
            int r2 = idx >> 6, c2 = idx & 63;
            sB[r2][c2] = B[(size_t)(k0 + r2) * N_DIM + bN + c2];
        }
        __syncthreads();
#pragma unroll
        for (int k = 0; k < 16; ++k) {
            float ar[4], br[4];
#pragma unroll
            for (int q = 0; q < 4; ++q) { ar[q] = sA[ty * 4 + q][k]; br[q] = sB[k][tx * 4 + q]; }
#pragma unroll
            for (int q = 0; q < 4; ++q)
#pragma unroll
                for (int w = 0; w < 4; ++w)
                    acc[q][w] += ar[q] * br[w];
        }
    }
#pragma unroll
    for (int q = 0; q < 4; ++q)
#pragma unroll
        for (int w = 0; w < 4; ++w)
            C[(size_t)(bM + ty * 4 + q) * N_DIM + bN + tx * 4 + w] = acc[q][w];
}

extern "C" void kernel_launch(void* const* d_in, const int* in_sizes, int n_in,
                              void* d_out, int out_size, void* d_ws, size_t ws_size,
                              hipStream_t stream) {
    const float* A = (const float*)d_in[0];
    const float* B = (const float*)d_in[1];
    float* C = (float*)d_out;

    size_t needA = (size_t)M_DIM * K_DIM * sizeof(unsigned short);
    size_t needB = (size_t)K_DIM * N_DIM * sizeof(unsigned short);

    if (ws_size >= needA + needB) {
        unsigned short* Aw = (unsigned short*)d_ws;
        unsigned short* Bw = Aw + (size_t)M_DIM * K_DIM;
        cvt_kernel<<<2048 + 4096, 256, 0, stream>>>(A, B, Aw, Bw);
        gemm8_kernel<<<(M_DIM / 256) * (N_DIM / 256), 512, 0, stream>>>(Aw, Bw, C);
    } else {
        sgemm_fb<<<dim3(N_DIM / 64, M_DIM / 64), dim3(16, 16), 0, stream>>>(A, B, C);
    }
}